// Round 12
// baseline (2401.453 us; speedup 1.0000x reference)
//
#include <hip/hip_runtime.h>
#include <stdint.h>

// LSTM B=64,T=512,I=512,H=512. out hs[T,B,H] fp32.
// R12 = R11 skeleton + early C-level poll issue + selective (monotonic-tag)
// retry + rcp-based activations.
// 8 groups x 8 batch rows; each group = 32 wgs x 16 h-cols (256 wgs, 256thr).
// Weights (K=1024=[w_ih|w_hh]) in regs as bf16 MFMA fragments, transposed-C:
// acc = mfma(W_frag, A_frag) -> lane's 4 acc regs = gates {i,f,g,o} of one
// (batch,col) -> lane-local cell update.
// h exchange: self-describing tagged u64 [data:32|tag:32], relaxed agent
// atomics (proven R7/R11). Poll: issue 8 u64 loads at STEP START (compiler
// places waitcnt at first use, after phase A); tags monotonic -> selective
// per-vector retry. ONE barrier/step. x_{t+2} reg prefetch post-barrier.
// out stores batched 8 steps in registers.

#define BATCH 64
#define TSTEPS 512
#define IDIM 512
#define HDIM 512
#define NGROUPS 8
#define BB 8                          // batch rows per group
#define NWG (NGROUPS * 32)            // 256 wgs
#define HDAT_U64 (BB * (HDIM / 2))    // 2048 u64 = 16KB per (parity,group)

typedef __attribute__((ext_vector_type(4))) float f32x4;
typedef __attribute__((ext_vector_type(8))) short bf16x8;
typedef __attribute__((ext_vector_type(2))) unsigned int u32x2;

#define AL(p) __hip_atomic_load((p), __ATOMIC_RELAXED, __HIP_MEMORY_SCOPE_AGENT)
#define AS(p, v) __hip_atomic_store((p), (v), __ATOMIC_RELAXED, __HIP_MEMORY_SCOPE_AGENT)

__device__ inline unsigned short f2bf(float f) {
  unsigned u = __builtin_bit_cast(unsigned, f);
  u = (u + 0x7fffu + ((u >> 16) & 1u)) >> 16;  // RNE
  return (unsigned short)u;
}
__device__ inline float fast_sigmoid(float x) {
  return __builtin_amdgcn_rcpf(1.f + __expf(-x));
}
__device__ inline float fast_tanh(float x) {
  return 1.f - 2.f * __builtin_amdgcn_rcpf(__expf(2.f * x) + 1.f);
}

__global__ void lstm_init(const float* __restrict__ b_ih, const float* __restrict__ b_hh,
                          float* __restrict__ bias, uint64_t* __restrict__ hdat) {
  const int i = blockIdx.x * blockDim.x + threadIdx.x;  // 2048 threads
  if (i < 4 * HDIM) bias[i] = b_ih[i] + b_hh[i];
  // zero tagged words (tag 0 never matches t>=1); clears graph-replay state
  for (int j = i; j < 2 * NGROUPS * HDAT_U64; j += 2048) hdat[j] = 0ull;
}

__global__ __launch_bounds__(256, 1)
void lstm_persistent(const float* __restrict__ x,
                     const float* __restrict__ w_ih,
                     const float* __restrict__ w_hh,
                     const float* __restrict__ bias,
                     uint64_t* hdat,     // [2][NGROUPS][BB][256] tagged pairs
                     float* __restrict__ out) {
  __shared__ unsigned short X_lds[2][8 * IDIM];   // 2 x 8KB, XOR-swizzled
  __shared__ unsigned short H_lds[2][8 * HDIM];   // 2 x 8KB, XOR-swizzled

  const int wg = blockIdx.x;
  const int group = wg >> 5;           // 0..7
  const int rank = wg & 31;
  const int b0 = group * BB;
  const int h0 = rank * 16;
  const int tid = threadIdx.x;
  const int wave = tid >> 6;
  const int lane = tid & 63;
  const int hi4 = lane >> 4;
  const int nn = lane & 15;

  // ---- one-time: weight A-fragments (transposed-C form) ----
  const int growf = (nn & 3) * HDIM + h0 + wave * 4 + (nn >> 2);  // gate row
  bf16x8 breg[32];
#pragma unroll
  for (int kt = 0; kt < 32; ++kt) {
    const int k = kt * 32 + hi4 * 8;
    const float* src = (k < IDIM) ? (w_ih + (size_t)growf * IDIM + k)
                                  : (w_hh + (size_t)growf * HDIM + (k - IDIM));
    bf16x8 v;
#pragma unroll
    for (int j = 0; j < 8; ++j) v[j] = (short)f2bf(src[j]);
    breg[kt] = v;
  }
  const int mycol = h0 + wave * 4 + hi4;
  const float bv0 = bias[0 * HDIM + mycol];
  const float bv1 = bias[1 * HDIM + mycol];
  const float bv2 = bias[2 * HDIM + mycol];
  const float bv3 = bias[3 * HDIM + mycol];

  const int bi = lane & 15;          // C col = batch (bi>=8 lanes are dupes)
  const int mr8 = bi & 7;            // MFMA B-row / LDS row (8 real rows)
  const int rswz = mr8 << 4;

  // ---- prologue: stage x_0 rows 0..7 -> X_lds[0]; preload xfA = x_1 ----
#pragma unroll
  for (int q = 0; q < 2; ++q) {
    const int r = wave + q * 4;
    const float* xp = x + ((size_t)(b0 + r) * TSTEPS + 0) * IDIM + lane * 8;
    float4 fa = *(const float4*)xp;
    float4 fb = *(const float4*)(xp + 4);
    bf16x8 v;
    v[0] = (short)f2bf(fa.x); v[1] = (short)f2bf(fa.y);
    v[2] = (short)f2bf(fa.z); v[3] = (short)f2bf(fa.w);
    v[4] = (short)f2bf(fb.x); v[5] = (short)f2bf(fb.y);
    v[6] = (short)f2bf(fb.z); v[7] = (short)f2bf(fb.w);
    *(bf16x8*)((char*)&X_lds[0][0] + ((r * 1024 + lane * 16) ^ ((r & 7) << 4))) = v;
  }
  float4 xfA[4], xfB[4];
#pragma unroll
  for (int q = 0; q < 2; ++q) {
    const float* xp = x + ((size_t)(b0 + wave + q * 4) * TSTEPS + 1) * IDIM + lane * 8;
    xfA[q * 2] = *(const float4*)xp;
    xfA[q * 2 + 1] = *(const float4*)(xp + 4);
  }
  __syncthreads();

  float c = 0.f;   // cell state for (batch=bi, col=mycol); bi>=8 lanes dup
  float hout[8];
  const size_t obase = (size_t)(b0 + bi) * HDIM + mycol;   // valid for bi<8

  for (int tb = 0; tb < TSTEPS; tb += 8) {
#pragma unroll
    for (int u = 0; u < 8; ++u) {
      const int t = tb + u;
      const int cur = t & 1;
      const uint32_t tu = (uint32_t)t;

      // ---- 1. EARLY poll issue: 8 u64 (C atomics; waitcnt lands at use) ----
      const uint64_t* dp = hdat + ((size_t)cur * NGROUPS + group) * HDAT_U64
                         + (size_t)wave * 512 + lane * 2;
      uint64_t hu0, hu1, hu2, hu3, hu4, hu5, hu6, hu7;
      if (t > 0) {
        hu0 = AL(dp);       hu1 = AL(dp + 1);
        hu2 = AL(dp + 128); hu3 = AL(dp + 129);
        hu4 = AL(dp + 256); hu5 = AL(dp + 257);
        hu6 = AL(dp + 384); hu7 = AL(dp + 385);
      }
      __builtin_amdgcn_sched_barrier(0);

      // ---- 2. stage x_{t+1} -> X_lds[cur^1] (independent of poll) ----
      if (t + 1 < TSTEPS) {
#pragma unroll
        for (int q = 0; q < 2; ++q) {
          float4 fa, fb;
          if ((u & 1) == 0) { fa = xfA[q * 2]; fb = xfA[q * 2 + 1]; }
          else              { fa = xfB[q * 2]; fb = xfB[q * 2 + 1]; }
          bf16x8 v;
          v[0] = (short)f2bf(fa.x); v[1] = (short)f2bf(fa.y);
          v[2] = (short)f2bf(fa.z); v[3] = (short)f2bf(fa.w);
          v[4] = (short)f2bf(fb.x); v[5] = (short)f2bf(fb.y);
          v[6] = (short)f2bf(fb.z); v[7] = (short)f2bf(fb.w);
          const int r = wave + q * 4;
          *(bf16x8*)((char*)&X_lds[cur ^ 1][0] + ((r * 1024 + lane * 16) ^ ((r & 7) << 4))) = v;
        }
      }

      // ---- 3. phase A: x-part MFMAs (kt 0..15) hide the poll flight ----
      f32x4 acc0 = {0.f, 0.f, 0.f, 0.f}, acc1 = {0.f, 0.f, 0.f, 0.f};
#pragma unroll
      for (int kt = 0; kt < 16; kt += 2) {
        bf16x8 a0 = *(const bf16x8*)((const char*)&X_lds[cur][0] +
                      ((mr8 * 1024 + (kt * 4 + hi4) * 16) ^ rswz));
        acc0 = __builtin_amdgcn_mfma_f32_16x16x32_bf16(breg[kt], a0, acc0, 0, 0, 0);
        bf16x8 a1 = *(const bf16x8*)((const char*)&X_lds[cur][0] +
                      ((mr8 * 1024 + ((kt + 1) * 4 + hi4) * 16) ^ rswz));
        acc1 = __builtin_amdgcn_mfma_f32_16x16x32_bf16(breg[kt + 1], a1, acc1, 0, 0, 0);
      }

      // ---- 4. tag check + SELECTIVE retry (tags monotonic) ----
      if (t > 0) {
        bool ok0 = false, ok1 = false, ok2 = false, ok3 = false;
        while (true) {
          if (!ok0) ok0 = __all((int)(((uint32_t)hu0 == tu) & ((uint32_t)hu1 == tu)));
          if (!ok1) ok1 = __all((int)(((uint32_t)hu2 == tu) & ((uint32_t)hu3 == tu)));
          if (!ok2) ok2 = __all((int)(((uint32_t)hu4 == tu) & ((uint32_t)hu5 == tu)));
          if (!ok3) ok3 = __all((int)(((uint32_t)hu6 == tu) & ((uint32_t)hu7 == tu)));
          if (ok0 & ok1 & ok2 & ok3) break;
          if (!ok0) { hu0 = AL(dp);       hu1 = AL(dp + 1); }
          if (!ok1) { hu2 = AL(dp + 128); hu3 = AL(dp + 129); }
          if (!ok2) { hu4 = AL(dp + 256); hu5 = AL(dp + 257); }
          if (!ok3) { hu6 = AL(dp + 384); hu7 = AL(dp + 385); }
        }
        // ---- 5. restage h -> H_lds[cur]: vec j -> row wave*2+(j>>1),
        //         half (j&1); byte row*1024+(j&1)*512+lane*8, swizzled ----
        {
          const int r0 = wave * 2;
          u32x2 w0 = { (uint32_t)(hu0 >> 32), (uint32_t)(hu1 >> 32) };
          u32x2 w1 = { (uint32_t)(hu2 >> 32), (uint32_t)(hu3 >> 32) };
          u32x2 w2 = { (uint32_t)(hu4 >> 32), (uint32_t)(hu5 >> 32) };
          u32x2 w3 = { (uint32_t)(hu6 >> 32), (uint32_t)(hu7 >> 32) };
          *(u32x2*)((char*)&H_lds[cur][0] + ((r0 * 1024 + lane * 8) ^ ((r0 & 7) << 4))) = w0;
          *(u32x2*)((char*)&H_lds[cur][0] + ((r0 * 1024 + 512 + lane * 8) ^ ((r0 & 7) << 4))) = w1;
          *(u32x2*)((char*)&H_lds[cur][0] + (((r0 + 1) * 1024 + lane * 8) ^ (((r0 + 1) & 7) << 4))) = w2;
          *(u32x2*)((char*)&H_lds[cur][0] + (((r0 + 1) * 1024 + 512 + lane * 8) ^ (((r0 + 1) & 7) << 4))) = w3;
        }
      }
      __syncthreads();   // the ONLY barrier per step

      // ---- 7. x_{t+2} refill issue (post-barrier: never drained by it) ----
      if (t + 2 < TSTEPS) {
#pragma unroll
        for (int q = 0; q < 2; ++q) {
          const float* xp = x + ((size_t)(b0 + wave + q * 4) * TSTEPS + (t + 2)) * IDIM + lane * 8;
          if ((u & 1) == 0) { xfB[q * 2] = *(const float4*)xp; xfB[q * 2 + 1] = *(const float4*)(xp + 4); }
          else              { xfA[q * 2] = *(const float4*)xp; xfA[q * 2 + 1] = *(const float4*)(xp + 4); }
        }
      }
      __builtin_amdgcn_sched_barrier(0);

      // ---- 8. phase C: h-part MFMAs (kt 16..31) ----
      if (t > 0) {
#pragma unroll
        for (int kt = 0; kt < 16; kt += 2) {
          bf16x8 a0 = *(const bf16x8*)((const char*)&H_lds[cur][0] +
                        ((mr8 * 1024 + (kt * 4 + hi4) * 16) ^ rswz));
          acc0 = __builtin_amdgcn_mfma_f32_16x16x32_bf16(breg[16 + kt], a0, acc0, 0, 0, 0);
          bf16x8 a1 = *(const bf16x8*)((const char*)&H_lds[cur][0] +
                        ((mr8 * 1024 + ((kt + 1) * 4 + hi4) * 16) ^ rswz));
          acc1 = __builtin_amdgcn_mfma_f32_16x16x32_bf16(breg[17 + kt], a1, acc1, 0, 0, 0);
        }
      }

      // ---- 9. elementwise: lane-local gates i,f,g,o in acc regs 0..3 ----
      const float gi = acc0[0] + acc1[0] + bv0;
      const float gf = acc0[1] + acc1[1] + bv1;
      const float gg = acc0[2] + acc1[2] + bv2;
      const float go = acc0[3] + acc1[3] + bv3;
      c = fast_sigmoid(gf) * c + fast_sigmoid(gi) * fast_tanh(gg);
      const float hval = fast_sigmoid(go) * fast_tanh(c);

      // ---- publish tagged h_{t+1}: single u64 store (untearable) ----
      if (t + 1 < TSTEPS) {
        const unsigned hb = (unsigned)f2bf(hval);
        const unsigned pb = (unsigned)__shfl_xor((int)hb, 16, 64);
        if (bi < 8 && (hi4 & 1) == 0) {
          const uint64_t val = (uint64_t)(uint32_t)(t + 1)
                             | ((uint64_t)(hb | (pb << 16)) << 32);
          AS(hdat + ((size_t)((t + 1) & 1) * NGROUPS + group) * HDAT_U64
               + (size_t)bi * 256 + (mycol >> 1), val);
        }
      }
      hout[u] = hval;   // static index (unrolled) -> stays in VGPRs
    }
    // ---- batched out flush (couples into a poll only once per 8 steps) ----
    if (bi < 8) {
#pragma unroll
      for (int k = 0; k < 8; ++k)
        out[(size_t)(tb + k) * (BATCH * HDIM) + obase] = hout[k];
    }
  }
}

extern "C" void kernel_launch(void* const* d_in, const int* in_sizes, int n_in,
                              void* d_out, int out_size, void* d_ws, size_t ws_size,
                              hipStream_t stream) {
  const float* x    = (const float*)d_in[0];
  const float* w_ih = (const float*)d_in[1];
  const float* w_hh = (const float*)d_in[2];
  const float* b_ih = (const float*)d_in[3];
  const float* b_hh = (const float*)d_in[4];
  float* out = (float*)d_out;

  char* ws = (char*)d_ws;
  float* bias = (float*)ws;                              // 8KB
  uint64_t* hdat = (uint64_t*)(ws + 8192);               // 256KB tagged pairs

  lstm_init<<<8, 256, 0, stream>>>(b_ih, b_hh, bias, hdat);
  lstm_persistent<<<NWG, 256, 0, stream>>>(x, w_ih, w_hh, bias, hdat, out);
}

// Round 13
// 1268.749 us; speedup vs baseline: 1.8928x; 1.8928x over previous
//
#include <hip/hip_runtime.h>
#include <stdint.h>

// LSTM B=64,T=512,I=512,H=512. out hs[T,B,H] fp32.
// R13 = R11 skeleton + SINGLE-POLLER WAVE (poll rounds are coherent-read-BW
// bound: 32 wgs x 16KB sc1 re-reads per group-round; wave0-only cuts 4x).
// 8 groups x 8 batch rows; each group = 32 wgs x 16 h-cols (256 wgs, 256thr).
// Weights (K=1024=[w_ih|w_hh]) in regs as bf16 MFMA fragments, transposed-C:
// acc = mfma(W_frag, A_frag) -> lane's 4 acc regs = gates {i,f,g,o} of one
// (batch,col) -> lane-local cell update.
// h exchange: self-describing tagged u64 [data:32|tag:32], relaxed agent
// atomics (proven R7/R11). Per step: phase A (x MFMAs), stage x_{t+1},
// wave0 polls 16KB (asm: 16x dwordx4 sc0 sc1 over 4 bases + vmcnt(0)),
// tag-verified full re-read, restages H_lds; ONE barrier; x_{t+2} prefetch;
// phase C (h MFMAs); elementwise (rcp activations); publish tagged u64.
// out stores batched 8 steps in registers.

#define BATCH 64
#define TSTEPS 512
#define IDIM 512
#define HDIM 512
#define NGROUPS 8
#define BB 8                          // batch rows per group
#define NWG (NGROUPS * 32)            // 256 wgs
#define HDAT_U64 (BB * (HDIM / 2))    // 2048 u64 = 16KB per (parity,group)

typedef __attribute__((ext_vector_type(4))) float f32x4;
typedef __attribute__((ext_vector_type(8))) short bf16x8;
typedef __attribute__((ext_vector_type(4))) unsigned int u32x4;
typedef __attribute__((ext_vector_type(2))) unsigned int u32x2;

#define AS(p, v) __hip_atomic_store((p), (v), __ATOMIC_RELAXED, __HIP_MEMORY_SCOPE_AGENT)

__device__ inline unsigned short f2bf(float f) {
  unsigned u = __builtin_bit_cast(unsigned, f);
  u = (u + 0x7fffu + ((u >> 16) & 1u)) >> 16;  // RNE
  return (unsigned short)u;
}
__device__ inline float fast_sigmoid(float x) {
  return __builtin_amdgcn_rcpf(1.f + __expf(-x));
}
__device__ inline float fast_tanh(float x) {
  return 1.f - 2.f * __builtin_amdgcn_rcpf(__expf(2.f * x) + 1.f);
}

__global__ void lstm_init(const float* __restrict__ b_ih, const float* __restrict__ b_hh,
                          float* __restrict__ bias, uint64_t* __restrict__ hdat) {
  const int i = blockIdx.x * blockDim.x + threadIdx.x;  // 2048 threads
  if (i < 4 * HDIM) bias[i] = b_ih[i] + b_hh[i];
  // zero tagged words (tag 0 never matches t>=1); clears graph-replay state
  for (int j = i; j < 2 * NGROUPS * HDAT_U64; j += 2048) hdat[j] = 0ull;
}

__global__ __launch_bounds__(256, 1)
void lstm_persistent(const float* __restrict__ x,
                     const float* __restrict__ w_ih,
                     const float* __restrict__ w_hh,
                     const float* __restrict__ bias,
                     uint64_t* hdat,     // [2][NGROUPS][BB][256] tagged pairs
                     float* __restrict__ out) {
  __shared__ unsigned short X_lds[2][8 * IDIM];   // 2 x 8KB, XOR-swizzled
  __shared__ unsigned short H_lds[2][8 * HDIM];   // 2 x 8KB, XOR-swizzled

  const int wg = blockIdx.x;
  const int group = wg >> 5;           // 0..7
  const int rank = wg & 31;
  const int b0 = group * BB;
  const int h0 = rank * 16;
  const int tid = threadIdx.x;
  const int wave = tid >> 6;
  const int lane = tid & 63;
  const int hi4 = lane >> 4;
  const int nn = lane & 15;

  // ---- one-time: weight A-fragments (transposed-C form) ----
  const int growf = (nn & 3) * HDIM + h0 + wave * 4 + (nn >> 2);  // gate row
  bf16x8 breg[32];
#pragma unroll
  for (int kt = 0; kt < 32; ++kt) {
    const int k = kt * 32 + hi4 * 8;
    const float* src = (k < IDIM) ? (w_ih + (size_t)growf * IDIM + k)
                                  : (w_hh + (size_t)growf * HDIM + (k - IDIM));
    bf16x8 v;
#pragma unroll
    for (int j = 0; j < 8; ++j) v[j] = (short)f2bf(src[j]);
    breg[kt] = v;
  }
  const int mycol = h0 + wave * 4 + hi4;
  const float bv0 = bias[0 * HDIM + mycol];
  const float bv1 = bias[1 * HDIM + mycol];
  const float bv2 = bias[2 * HDIM + mycol];
  const float bv3 = bias[3 * HDIM + mycol];

  const int bi = lane & 15;          // C col = batch (bi>=8 lanes are dupes)
  const int mr8 = bi & 7;            // MFMA B-row / LDS row (8 real rows)
  const int rswz = mr8 << 4;

  // ---- prologue: stage x_0 rows 0..7 -> X_lds[0]; preload xfA = x_1 ----
#pragma unroll
  for (int q = 0; q < 2; ++q) {
    const int r = wave + q * 4;
    const float* xp = x + ((size_t)(b0 + r) * TSTEPS + 0) * IDIM + lane * 8;
    float4 fa = *(const float4*)xp;
    float4 fb = *(const float4*)(xp + 4);
    bf16x8 v;
    v[0] = (short)f2bf(fa.x); v[1] = (short)f2bf(fa.y);
    v[2] = (short)f2bf(fa.z); v[3] = (short)f2bf(fa.w);
    v[4] = (short)f2bf(fb.x); v[5] = (short)f2bf(fb.y);
    v[6] = (short)f2bf(fb.z); v[7] = (short)f2bf(fb.w);
    *(bf16x8*)((char*)&X_lds[0][0] + ((r * 1024 + lane * 16) ^ ((r & 7) << 4))) = v;
  }
  float4 xfA[4], xfB[4];
#pragma unroll
  for (int q = 0; q < 2; ++q) {
    const float* xp = x + ((size_t)(b0 + wave + q * 4) * TSTEPS + 1) * IDIM + lane * 8;
    xfA[q * 2] = *(const float4*)xp;
    xfA[q * 2 + 1] = *(const float4*)(xp + 4);
  }
  __syncthreads();

  float c = 0.f;   // cell state for (batch=bi, col=mycol); bi>=8 lanes dup
  float hout[8];
  const size_t obase = (size_t)(b0 + bi) * HDIM + mycol;   // valid for bi<8

  for (int tb = 0; tb < TSTEPS; tb += 8) {
#pragma unroll
    for (int u = 0; u < 8; ++u) {
      const int t = tb + u;
      const int cur = t & 1;
      const uint32_t tu = (uint32_t)t;

      // ---- 1. phase A: x-part MFMAs (kt 0..15) ----
      f32x4 acc0 = {0.f, 0.f, 0.f, 0.f}, acc1 = {0.f, 0.f, 0.f, 0.f};
#pragma unroll
      for (int kt = 0; kt < 16; kt += 2) {
        bf16x8 a0 = *(const bf16x8*)((const char*)&X_lds[cur][0] +
                      ((mr8 * 1024 + (kt * 4 + hi4) * 16) ^ rswz));
        acc0 = __builtin_amdgcn_mfma_f32_16x16x32_bf16(breg[kt], a0, acc0, 0, 0, 0);
        bf16x8 a1 = *(const bf16x8*)((const char*)&X_lds[cur][0] +
                      ((mr8 * 1024 + ((kt + 1) * 4 + hi4) * 16) ^ rswz));
        acc1 = __builtin_amdgcn_mfma_f32_16x16x32_bf16(breg[kt + 1], a1, acc1, 0, 0, 0);
      }

      // ---- 2. stage x_{t+1} -> X_lds[cur^1] (all waves; widens the
      //         publish->poll gap and clears the post-poll path) ----
      if (t + 1 < TSTEPS) {
#pragma unroll
        for (int q = 0; q < 2; ++q) {
          float4 fa, fb;
          if ((u & 1) == 0) { fa = xfA[q * 2]; fb = xfA[q * 2 + 1]; }
          else              { fa = xfB[q * 2]; fb = xfB[q * 2 + 1]; }
          bf16x8 v;
          v[0] = (short)f2bf(fa.x); v[1] = (short)f2bf(fa.y);
          v[2] = (short)f2bf(fa.z); v[3] = (short)f2bf(fa.w);
          v[4] = (short)f2bf(fb.x); v[5] = (short)f2bf(fb.y);
          v[6] = (short)f2bf(fb.z); v[7] = (short)f2bf(fb.w);
          const int r = wave + q * 4;
          *(bf16x8*)((char*)&X_lds[cur ^ 1][0] + ((r * 1024 + lane * 16) ^ ((r & 7) << 4))) = v;
        }
      }

      // ---- 3. WAVE 0 ONLY: poll the whole 16KB + restage H_lds ----
      if (wave == 0 && t > 0) {
        const uint64_t* dpb = hdat + ((size_t)cur * NGROUPS + group) * HDAT_U64
                            + (size_t)lane * 2;
        const uint64_t* dp0 = dpb;
        const uint64_t* dp1 = dpb + 512;
        const uint64_t* dp2 = dpb + 1024;
        const uint64_t* dp3 = dpb + 1536;
        u32x4 d0, d1, d2, d3, d4, d5, d6, d7, d8, d9, d10, d11, d12, d13, d14, d15;
        while (true) {
          asm volatile(
            "global_load_dwordx4 %0,  %16, off sc0 sc1\n\t"
            "global_load_dwordx4 %1,  %16, off offset:1024 sc0 sc1\n\t"
            "global_load_dwordx4 %2,  %16, off offset:2048 sc0 sc1\n\t"
            "global_load_dwordx4 %3,  %16, off offset:3072 sc0 sc1\n\t"
            "global_load_dwordx4 %4,  %17, off sc0 sc1\n\t"
            "global_load_dwordx4 %5,  %17, off offset:1024 sc0 sc1\n\t"
            "global_load_dwordx4 %6,  %17, off offset:2048 sc0 sc1\n\t"
            "global_load_dwordx4 %7,  %17, off offset:3072 sc0 sc1\n\t"
            "global_load_dwordx4 %8,  %18, off sc0 sc1\n\t"
            "global_load_dwordx4 %9,  %18, off offset:1024 sc0 sc1\n\t"
            "global_load_dwordx4 %10, %18, off offset:2048 sc0 sc1\n\t"
            "global_load_dwordx4 %11, %18, off offset:3072 sc0 sc1\n\t"
            "global_load_dwordx4 %12, %19, off sc0 sc1\n\t"
            "global_load_dwordx4 %13, %19, off offset:1024 sc0 sc1\n\t"
            "global_load_dwordx4 %14, %19, off offset:2048 sc0 sc1\n\t"
            "global_load_dwordx4 %15, %19, off offset:3072 sc0 sc1\n\t"
            "s_waitcnt vmcnt(0)"
            : "=&v"(d0), "=&v"(d1), "=&v"(d2), "=&v"(d3),
              "=&v"(d4), "=&v"(d5), "=&v"(d6), "=&v"(d7),
              "=&v"(d8), "=&v"(d9), "=&v"(d10), "=&v"(d11),
              "=&v"(d12), "=&v"(d13), "=&v"(d14), "=&v"(d15)
            : "v"(dp0), "v"(dp1), "v"(dp2), "v"(dp3)
            : "memory");
          __builtin_amdgcn_sched_barrier(0);
          bool ok = (d0[0] == tu) & (d0[2] == tu) & (d1[0] == tu) & (d1[2] == tu)
                  & (d2[0] == tu) & (d2[2] == tu) & (d3[0] == tu) & (d3[2] == tu)
                  & (d4[0] == tu) & (d4[2] == tu) & (d5[0] == tu) & (d5[2] == tu)
                  & (d6[0] == tu) & (d6[2] == tu) & (d7[0] == tu) & (d7[2] == tu)
                  & (d8[0] == tu) & (d8[2] == tu) & (d9[0] == tu) & (d9[2] == tu)
                  & (d10[0] == tu) & (d10[2] == tu) & (d11[0] == tu) & (d11[2] == tu)
                  & (d12[0] == tu) & (d12[2] == tu) & (d13[0] == tu) & (d13[2] == tu)
                  & (d14[0] == tu) & (d14[2] == tu) & (d15[0] == tu) & (d15[2] == tu);
          if (__all((int)ok)) break;
        }
        // restage: load i covers row = i>>1, half = i&1;
        // byte = row*1024 + (i&1)*512 + lane*8, swizzle ^((row&7)<<4).
#define RST(i, di)                                                           \
        {                                                                    \
          const int row_ = (i) >> 1;                                         \
          u32x2 w_ = { di[1], di[3] };                                       \
          *(u32x2*)((char*)&H_lds[cur][0] +                                  \
            ((row_ * 1024 + ((i) & 1) * 512 + lane * 8) ^ ((row_ & 7) << 4))) = w_; \
        }
        RST(0, d0)  RST(1, d1)  RST(2, d2)  RST(3, d3)
        RST(4, d4)  RST(5, d5)  RST(6, d6)  RST(7, d7)
        RST(8, d8)  RST(9, d9)  RST(10, d10) RST(11, d11)
        RST(12, d12) RST(13, d13) RST(14, d14) RST(15, d15)
#undef RST
      }
      __syncthreads();   // the ONLY barrier per step

      // ---- 4. x_{t+2} refill issue (post-barrier: never drained by it) ----
      if (t + 2 < TSTEPS) {
#pragma unroll
        for (int q = 0; q < 2; ++q) {
          const float* xp = x + ((size_t)(b0 + wave + q * 4) * TSTEPS + (t + 2)) * IDIM + lane * 8;
          if ((u & 1) == 0) { xfB[q * 2] = *(const float4*)xp; xfB[q * 2 + 1] = *(const float4*)(xp + 4); }
          else              { xfA[q * 2] = *(const float4*)xp; xfA[q * 2 + 1] = *(const float4*)(xp + 4); }
        }
      }
      __builtin_amdgcn_sched_barrier(0);

      // ---- 5. phase C: h-part MFMAs (kt 16..31) ----
      if (t > 0) {
#pragma unroll
        for (int kt = 0; kt < 16; kt += 2) {
          bf16x8 a0 = *(const bf16x8*)((const char*)&H_lds[cur][0] +
                        ((mr8 * 1024 + (kt * 4 + hi4) * 16) ^ rswz));
          acc0 = __builtin_amdgcn_mfma_f32_16x16x32_bf16(breg[16 + kt], a0, acc0, 0, 0, 0);
          bf16x8 a1 = *(const bf16x8*)((const char*)&H_lds[cur][0] +
                        ((mr8 * 1024 + ((kt + 1) * 4 + hi4) * 16) ^ rswz));
          acc1 = __builtin_amdgcn_mfma_f32_16x16x32_bf16(breg[17 + kt], a1, acc1, 0, 0, 0);
        }
      }

      // ---- 6. elementwise: lane-local gates i,f,g,o in acc regs 0..3 ----
      const float gi = acc0[0] + acc1[0] + bv0;
      const float gf = acc0[1] + acc1[1] + bv1;
      const float gg = acc0[2] + acc1[2] + bv2;
      const float go = acc0[3] + acc1[3] + bv3;
      c = fast_sigmoid(gf) * c + fast_sigmoid(gi) * fast_tanh(gg);
      const float hval = fast_sigmoid(go) * fast_tanh(c);

      // ---- 7. publish tagged h_{t+1}: single u64 store (untearable) ----
      if (t + 1 < TSTEPS) {
        const unsigned hb = (unsigned)f2bf(hval);
        const unsigned pb = (unsigned)__shfl_xor((int)hb, 16, 64);
        if (bi < 8 && (hi4 & 1) == 0) {
          const uint64_t val = (uint64_t)(uint32_t)(t + 1)
                             | ((uint64_t)(hb | (pb << 16)) << 32);
          AS(hdat + ((size_t)((t + 1) & 1) * NGROUPS + group) * HDAT_U64
               + (size_t)bi * 256 + (mycol >> 1), val);
        }
      }
      hout[u] = hval;   // static index (unrolled) -> stays in VGPRs
    }
    // ---- batched out flush (couples into a poll only once per 8 steps) ----
    if (bi < 8) {
#pragma unroll
      for (int k = 0; k < 8; ++k)
        out[(size_t)(tb + k) * (BATCH * HDIM) + obase] = hout[k];
    }
  }
}

extern "C" void kernel_launch(void* const* d_in, const int* in_sizes, int n_in,
                              void* d_out, int out_size, void* d_ws, size_t ws_size,
                              hipStream_t stream) {
  const float* x    = (const float*)d_in[0];
  const float* w_ih = (const float*)d_in[1];
  const float* w_hh = (const float*)d_in[2];
  const float* b_ih = (const float*)d_in[3];
  const float* b_hh = (const float*)d_in[4];
  float* out = (float*)d_out;

  char* ws = (char*)d_ws;
  float* bias = (float*)ws;                              // 8KB
  uint64_t* hdat = (uint64_t*)(ws + 8192);               // 256KB tagged pairs

  lstm_init<<<8, 256, 0, stream>>>(b_ih, b_hh, bias, hdat);
  lstm_persistent<<<NWG, 256, 0, stream>>>(x, w_ih, w_hh, bias, hdat, out);
}